// Round 19
// baseline (89.268 us; speedup 1.0000x reference)
//
#include <hip/hip_runtime.h>
#include <hip/hip_bf16.h>
#include <cstdint>
#include <cstddef>

// RBF Gram matrix: K[i,j] = exp(-gamma * ||a_i - b_j||^2), A,B: [8192,256] f32.
// Out: [8192,8192] f32.
//
// Round-19: pair-window K-loop. m233 mechanism: in 2-phase loops the
// stage+vmcnt+barrier BOUNDARY is ~72% of the critical path. All prior
// rounds kept one boundary per BK=32 K-step (36 rendezvous/block). Here:
// LDS = 4 x 16KB units; window w computes K-steps {2w,2w+1} from pair w&1
// and stages the OTHER pair (steps {2w+2,2w+3}) FIRST (8 gloads get the
// whole window's 16 ds_read + 32 MFMA to land); ONE vmcnt(0)+s_barrier per
// window -> boundaries halve (4/tile + prologue). Everything else is R18
// verbatim: TPB=4 tile chain, 16KB unit layout, staging involution
// f(b)=b^(((b>>7)&3)<<4) (bank conflicts measured 0), swapped-operand MFMA
// C-mapping, lean exp2 epilogue, XCD region map.

#define GAMMA_F 0.00390625f
#define LOG2E_F 1.44269504088896340736f

typedef __attribute__((ext_vector_type(8))) short short8;   // 8 bf16
typedef __attribute__((ext_vector_type(4))) float f32x4;    // acc / 16B

constexpr int KD = 256;
constexpr int ND = 8192;
constexpr int NKT = KD / 32;   // 8 K-steps of BK=32
constexpr int TPB = 4;         // tiles per block (consecutive tile-cols)

__device__ __forceinline__ unsigned short f2b(float f) {
  unsigned int u = __float_as_uint(f);
  u += 0x7FFFu + ((u >> 16) & 1u);
  return (unsigned short)(u >> 16);
}

// Raw v_exp_f32: exact for our arg range [-8, 0].
__device__ __forceinline__ float fast_exp2(float x) {
#if __has_builtin(__builtin_amdgcn_exp2f)
  return __builtin_amdgcn_exp2f(x);
#else
  float r;
  asm volatile("v_exp_f32 %0, %1\n\ts_nop 1" : "=v"(r) : "v"(x));
  return r;
#endif
}

__device__ __forceinline__ void gload_lds16(const void* g, void* l) {
  __builtin_amdgcn_global_load_lds(
      (const __attribute__((address_space(1))) unsigned int*)g,
      (__attribute__((address_space(3))) unsigned int*)l, 16, 0, 0);
}

#define FULL_BARRIER() do { asm volatile("" ::: "memory"); \
  __builtin_amdgcn_s_barrier(); asm volatile("" ::: "memory"); } while (0)

// ---------------------------------------------------------------------------
// Prepass: pre-scaled row norms n = -gamma*log2e*||row||^2 + bf16 convert.
// ---------------------------------------------------------------------------
__global__ __launch_bounds__(256) void norm_convert_kernel(
    const float* __restrict__ A, const float* __restrict__ B,
    unsigned short* Abf, unsigned short* Bbf,
    float* __restrict__ na, float* __restrict__ nb)
{
  const int lane = threadIdx.x & 63;
  const int row = blockIdx.x * 4 + (threadIdx.x >> 6);
  const float* src = A;
  unsigned short* dst = Abf;
  float* nrm = na;
  int r = row;
  if (row >= ND) { src = B; dst = Bbf; nrm = nb; r = row - ND; }

  const float4 v = *(const float4*)(src + (size_t)r * KD + lane * 4);
  float s = v.x * v.x + v.y * v.y + v.z * v.z + v.w * v.w;
  #pragma unroll
  for (int off = 32; off >= 1; off >>= 1) s += __shfl_xor(s, off, 64);

  if (dst) {
    const unsigned int p0 = (unsigned)f2b(v.x) | ((unsigned)f2b(v.y) << 16);
    const unsigned int p1 = (unsigned)f2b(v.z) | ((unsigned)f2b(v.w) << 16);
    *(uint2*)(dst + (size_t)r * KD + lane * 4) = make_uint2(p0, p1);
  }
  if (lane == 0) nrm[r] = -GAMMA_F * LOG2E_F * s;
}

// ---------------------------------------------------------------------------
// Main 128x128 GEMM + RBF epilogue, pair-window pipeline, TPB=4 chain.
// 256 threads = 4 waves (2x2); wave owns 64x64 (acc[4][4]).
// LDS: 4 units x 16KB = 64KB. Unit u at u*16384: A-step @0, B-step @8192.
// ---------------------------------------------------------------------------
__global__ __launch_bounds__(256, 2) void rbf_gemm_kernel(
    const unsigned short* __restrict__ Abf, const unsigned short* __restrict__ Bbf,
    const float* __restrict__ na, const float* __restrict__ nb,
    float* __restrict__ C)
{
  __shared__ __align__(16) char smem[65536];
  const int t = threadIdx.x;
  const int lane = t & 63;
  const int wid = t >> 6;
  const int wm = wid >> 1, wn = wid & 1;

  // XCD mapping (bijective, 8 XCDs x 128 blocks): 16-tile-row x 8-tile-quad
  // region per XCD -> ~2MB B + 1MB A panels resident in the XCD L2.
  const int bid = blockIdx.x;
  const int x = bid & 7;
  const int k = bid >> 3;                       // 0..127
  const int tr = ((x >> 1) << 4) + (k >> 3);    // tile row 0..63
  const int tcq = ((x & 1) << 3) + (k & 7);     // tile quad 0..15
  const int brow = tr << 7;
  const int tc0 = tcq << 2;

  // Staging: linear dest chunk + t*16; GLOBAL source col swizzled by the
  // involution f(b)=b^(((b>>7)&3)<<4) -> scolb = ((t&3)^((t>>3)&3))<<4.
  const int srow = t >> 2;                                   // 0..63
  const int scolb = (((t & 3) ^ ((t >> 3) & 3)) << 4);

  // Fragment ds_read offsets (within a 16KB unit; add unit*16384 at use).
  int aoff[4], boff[4];
  #pragma unroll
  for (int f = 0; f < 4; ++f) {
    const int ra = wm * 64 + f * 16 + (lane & 15);
    aoff[f] = ra * 64 + (((lane >> 4) * 16) ^ (((ra >> 1) & 3) << 4));
    const int rb = wn * 64 + f * 16 + (lane & 15);
    boff[f] = 8192 + rb * 64 + (((lane >> 4) * 16) ^ (((rb >> 1) & 3) << 4));
  }

  const char* Ab = (const char*)Abf;
  const char* Bb = (const char*)Bbf;
  const float c2 = 2.0f * GAMMA_F * LOG2E_F;

  auto stage = [&](int unit, int kt, int bcol) {
    #pragma unroll
    for (int h = 0; h < 2; ++h) {
      gload_lds16(Ab + (size_t)(brow + h * 64 + srow) * 512 + kt * 64 + scolb,
                  smem + unit * 16384 + h * 4096 + (wid << 10));
      gload_lds16(Bb + (size_t)(bcol + h * 64 + srow) * 512 + kt * 64 + scolb,
                  smem + unit * 16384 + 8192 + h * 4096 + (wid << 10));
    }
  };

  // One K-step: frags from unit u, 16 MFMA into acc.
  auto kstep = [&](int u, f32x4 (&acc)[4][4]) {
    const int cb = u * 16384;
    short8 af[4], bfv[4];
    #pragma unroll
    for (int f = 0; f < 4; ++f) {
      af[f]  = *(const short8*)(smem + cb + aoff[f]);
      bfv[f] = *(const short8*)(smem + cb + boff[f]);
    }
    __builtin_amdgcn_s_setprio(1);
    // Swapped operands: thread holds C[i][j0..j0+3].
    #pragma unroll
    for (int fm = 0; fm < 4; ++fm)
      #pragma unroll
      for (int fn = 0; fn < 4; ++fn)
        acc[fm][fn] = __builtin_amdgcn_mfma_f32_16x16x32_bf16(
            bfv[fn], af[fm], acc[fm][fn], 0, 0, 0);
    __builtin_amdgcn_s_setprio(0);
  };

  #pragma unroll
  for (int t4 = 0; t4 < TPB; ++t4) {
    const int bcol = (tc0 + t4) << 7;
    f32x4 acc[4][4] = {};

    // ---- prologue: stage pair 0 (units 0,1 = K-steps 0,1) ----
    stage(0, 0, bcol);
    stage(1, 1, bcol);
    asm volatile("s_waitcnt vmcnt(0)" ::: "memory");
    FULL_BARRIER();

    // ---- pair-window loop: 4 windows, ONE boundary each ----
    #pragma unroll
    for (int w = 0; w < NKT / 2; ++w) {
      const int P = w & 1;
      // Stage the other pair FIRST (max time to land under this window).
      if (w + 1 < NKT / 2) {
        stage(2 * (P ^ 1),     2 * w + 2, bcol);
        stage(2 * (P ^ 1) + 1, 2 * w + 3, bcol);
      }
      kstep(2 * P, acc);         // K-step 2w
      kstep(2 * P + 1, acc);     // K-step 2w+1
      if (w + 1 < NKT / 2) {
        asm volatile("s_waitcnt vmcnt(0)" ::: "memory");
        FULL_BARRIER();
      }
    }

    // ---- lean epilogue: K = exp2(na + nb + 2*gamma*log2e*dot) ----
    f32x4 b4s[4];
    #pragma unroll
    for (int fn = 0; fn < 4; ++fn) {
      const int j0 = bcol + wn * 64 + fn * 16 + ((lane >> 4) << 2);
      b4s[fn] = *(const f32x4*)&nb[j0];
    }
    #pragma unroll
    for (int fm = 0; fm < 4; ++fm) {
      const int i = brow + wm * 64 + fm * 16 + (lane & 15);
      const float an = na[i];
      float* crow = C + (size_t)i * ND;
      #pragma unroll
      for (int fn = 0; fn < 4; ++fn) {
        const int j0 = bcol + wn * 64 + fn * 16 + ((lane >> 4) << 2);
        f32x4 arg = b4s[fn] + an;          // v_pk_add_f32 x2
        arg = acc[fm][fn] * c2 + arg;      // v_pk_fma_f32 x2
        f32x4 o;
        o[0] = fast_exp2(arg[0]);
        o[1] = fast_exp2(arg[1]);
        o[2] = fast_exp2(arg[2]);
        o[3] = fast_exp2(arg[3]);
        *(f32x4*)&crow[j0] = o;
      }
    }

    // ---- tile boundary: drain stores + protect LDS before next tile ----
    if (t4 + 1 < TPB) __syncthreads();
  }
}

// ---------------------------------------------------------------------------
// Fallback (tiny d_ws): 128x128 serial kernel, f32->bf16 inline.
// ---------------------------------------------------------------------------
__global__ __launch_bounds__(256) void rbf_gemm_fallback(
    const float* __restrict__ Af, const float* __restrict__ Bf,
    const float* __restrict__ na, const float* __restrict__ nb,
    float* __restrict__ C)
{
  __shared__ __align__(16) char smem[16384];
  const int t = threadIdx.x;
  const int lane = t & 63;
  const int wid = t >> 6;
  const int wm = wid >> 1, wn = wid & 1;
  const int bid = blockIdx.x;
  const int brow = (bid >> 6) << 7;
  const int bcol = (bid & 63) << 7;
  const int srow = t >> 2;
  const int scolb = (((t & 3) ^ ((t >> 3) & 3)) << 4);

  int aoff[4], boff[4];
  #pragma unroll
  for (int f = 0; f < 4; ++f) {
    const int ra = wm * 64 + f * 16 + (lane & 15);
    aoff[f] = ra * 64 + (((lane >> 4) * 16) ^ (((ra >> 1) & 3) << 4));
    const int rb = wn * 64 + f * 16 + (lane & 15);
    boff[f] = 8192 + rb * 64 + (((lane >> 4) * 16) ^ (((rb >> 1) & 3) << 4));
  }

  f32x4 acc[4][4] = {};
  for (int kt = 0; kt < 8; ++kt) {
    #pragma unroll
    for (int h = 0; h < 2; ++h) {
      const float* sa = Af + (size_t)(brow + h * 64 + srow) * KD + kt * 32 + (scolb >> 1);
      const float4 a0 = *(const float4*)sa;
      const float4 a1 = *(const float4*)(sa + 4);
      *(uint4*)(smem + h * 4096 + t * 16) = make_uint4(
          (unsigned)f2b(a0.x) | ((unsigned)f2b(a0.y) << 16),
          (unsigned)f2b(a0.z) | ((unsigned)f2b(a0.w) << 16),
          (unsigned)f2b(a1.x) | ((unsigned)f2b(a1.y) << 16),
          (unsigned)f2b(a1.z) | ((unsigned)f2b(a1.w) << 16));
      const float* sb = Bf + (size_t)(bcol + h * 64 + srow) * KD + kt * 32 + (scolb >> 1);
      const float4 b0 = *(const float4*)sb;
      const float4 b1 = *(const float4*)(sb + 4);
      *(uint4*)(smem + 8192 + h * 4096 + t * 16) = make_uint4(
          (unsigned)f2b(b0.x) | ((unsigned)f2b(b0.y) << 16),
          (unsigned)f2b(b0.z) | ((unsigned)f2b(b0.w) << 16),
          (unsigned)f2b(b1.x) | ((unsigned)f2b(b1.y) << 16),
          (unsigned)f2b(b1.z) | ((unsigned)f2b(b1.w) << 16));
    }
    __syncthreads();
    short8 af[4], bfv[4];
    #pragma unroll
    for (int f = 0; f < 4; ++f) {
      af[f]  = *(const short8*)(smem + aoff[f]);
      bfv[f] = *(const short8*)(smem + boff[f]);
    }
    #pragma unroll
    for (int fm = 0; fm < 4; ++fm)
      #pragma unroll
      for (int fn = 0; fn < 4; ++fn)
        acc[fm][fn] = __builtin_amdgcn_mfma_f32_16x16x32_bf16(
            bfv[fn], af[fm], acc[fm][fn], 0, 0, 0);
    __syncthreads();
  }

  const float c2 = 2.0f * GAMMA_F * LOG2E_F;
  #pragma unroll
  for (int fm = 0; fm < 4; ++fm) {
    const int i = brow + wm * 64 + fm * 16 + (lane & 15);
    const float an = na[i];
    float* crow = C + (size_t)i * ND;
    #pragma unroll
    for (int fn = 0; fn < 4; ++fn) {
      const int j0 = bcol + wn * 64 + fn * 16 + ((lane >> 4) << 2);
      const f32x4 b4 = *(const f32x4*)&nb[j0];
      f32x4 arg = b4 + an;
      arg = acc[fm][fn] * c2 + arg;
      f32x4 o;
      o[0] = fast_exp2(arg[0]);
      o[1] = fast_exp2(arg[1]);
      o[2] = fast_exp2(arg[2]);
      o[3] = fast_exp2(arg[3]);
      *(f32x4*)&crow[j0] = o;
    }
  }
}

// ---------------------------------------------------------------------------
extern "C" void kernel_launch(void* const* d_in, const int* in_sizes, int n_in,
                              void* d_out, int out_size, void* d_ws, size_t ws_size,
                              hipStream_t stream) {
  const float* A = (const float*)d_in[0];
  const float* B = (const float*)d_in[1];
  float* C = (float*)d_out;

  const size_t bfBytes = (size_t)ND * KD * 2;   // 4 MiB per matrix
  const size_t normBytes = (size_t)ND * 4;
  char* ws = (char*)d_ws;

  if (ws_size >= 2 * bfBytes + 2 * normBytes) {
    unsigned short* Abf = (unsigned short*)ws;
    unsigned short* Bbf = (unsigned short*)(ws + bfBytes);
    float* na = (float*)(ws + 2 * bfBytes);
    float* nb = (float*)(ws + 2 * bfBytes + normBytes);
    hipLaunchKernelGGL(norm_convert_kernel, dim3(2 * ND / 4), dim3(256), 0, stream,
                       A, B, Abf, Bbf, na, nb);
    hipLaunchKernelGGL(rbf_gemm_kernel, dim3((ND / 128) * (ND / 128) / TPB), dim3(256), 0,
                       stream, Abf, Bbf, na, nb, C);
  } else {
    float* na = (float*)ws;
    float* nb = (float*)(ws + normBytes);
    hipLaunchKernelGGL(norm_convert_kernel, dim3(2 * ND / 4), dim3(256), 0, stream,
                       A, B, (unsigned short*)nullptr, (unsigned short*)nullptr, na, nb);
    hipLaunchKernelGGL(rbf_gemm_fallback, dim3((ND / 128) * (ND / 128)), dim3(256), 0,
                       stream, A, B, na, nb, C);
  }
}

// Round 20
// 84.237 us; speedup vs baseline: 1.0597x; 1.0597x over previous
//
#include <hip/hip_runtime.h>
#include <hip/hip_bf16.h>
#include <cstdint>
#include <cstddef>

// RBF Gram matrix: K[i,j] = exp(-gamma * ||a_i - b_j||^2), A,B: [8192,256] f32.
// Out: [8192,8192] f32.
//
// Round-20: REVERT to round-13 exactly (best measured: 84.0us, absmax
// 1.95e-3). R19's pair-window (89.3) regressed: 64KB LDS halved block
// residency and full vmcnt(0) window drains cost more than the removed
// rendezvous saved. R13 = 128x128 tile, 4 waves, triple-buffered 48KB LDS
// counted-vmcnt pipeline (never 0 in-loop), involution staging (bank
// conflicts measured 0), swapped-operand MFMA, lean epilogue (raw
// v_exp_f32, packed f32 math), XCD 16x32-tile regions.
// Thirteen structural variants (R7-R19) span 84-115us with no saturated
// pipe; this is the best-measured point of that plateau.

#define GAMMA_F 0.00390625f
#define LOG2E_F 1.44269504088896340736f

typedef __attribute__((ext_vector_type(8))) short short8;   // 8 bf16
typedef __attribute__((ext_vector_type(4))) float f32x4;    // acc / 16B

constexpr int KD = 256;
constexpr int ND = 8192;
constexpr int NKT = KD / 32;   // 8 K-steps of BK=32

__device__ __forceinline__ unsigned short f2b(float f) {
  unsigned int u = __float_as_uint(f);
  u += 0x7FFFu + ((u >> 16) & 1u);
  return (unsigned short)(u >> 16);
}

// Raw v_exp_f32: exact for our arg range [-8, 0] (all results normal).
__device__ __forceinline__ float fast_exp2(float x) {
#if __has_builtin(__builtin_amdgcn_exp2f)
  return __builtin_amdgcn_exp2f(x);
#else
  float r;
  asm volatile("v_exp_f32 %0, %1\n\ts_nop 1" : "=v"(r) : "v"(x));
  return r;
#endif
}

__device__ __forceinline__ void gload_lds16(const void* g, void* l) {
  __builtin_amdgcn_global_load_lds(
      (const __attribute__((address_space(1))) unsigned int*)g,
      (__attribute__((address_space(3))) unsigned int*)l, 16, 0, 0);
}

#define FULL_BARRIER() do { asm volatile("" ::: "memory"); \
  __builtin_amdgcn_s_barrier(); asm volatile("" ::: "memory"); } while (0)

// ---------------------------------------------------------------------------
// Prepass: pre-scaled row norms n = -gamma*log2e*||row||^2 + bf16 convert.
// ---------------------------------------------------------------------------
__global__ __launch_bounds__(256) void norm_convert_kernel(
    const float* __restrict__ A, const float* __restrict__ B,
    unsigned short* Abf, unsigned short* Bbf,
    float* __restrict__ na, float* __restrict__ nb)
{
  const int lane = threadIdx.x & 63;
  const int row = blockIdx.x * 4 + (threadIdx.x >> 6);
  const float* src = A;
  unsigned short* dst = Abf;
  float* nrm = na;
  int r = row;
  if (row >= ND) { src = B; dst = Bbf; nrm = nb; r = row - ND; }

  const float4 v = *(const float4*)(src + (size_t)r * KD + lane * 4);
  float s = v.x * v.x + v.y * v.y + v.z * v.z + v.w * v.w;
  #pragma unroll
  for (int off = 32; off >= 1; off >>= 1) s += __shfl_xor(s, off, 64);

  if (dst) {
    const unsigned int p0 = (unsigned)f2b(v.x) | ((unsigned)f2b(v.y) << 16);
    const unsigned int p1 = (unsigned)f2b(v.z) | ((unsigned)f2b(v.w) << 16);
    *(uint2*)(dst + (size_t)r * KD + lane * 4) = make_uint2(p0, p1);
  }
  if (lane == 0) nrm[r] = -GAMMA_F * LOG2E_F * s;
}

// ---------------------------------------------------------------------------
// Main 128x128 GEMM + RBF epilogue. 256 threads = 4 waves (2x2); wave owns
// 64x64 (acc[4][4]). LDS: 3 bufs x 16KB = 48KB -> 3 blocks/CU.
//
// Pipeline (T4): step k reads buf k%3, stages step k+2 into buf (k+2)%3,
// boundary waits vmcnt(4); vmcnt never drains to 0 in the steady loop.
// ---------------------------------------------------------------------------
__global__ __launch_bounds__(256, 3) void rbf_gemm_kernel(
    const unsigned short* __restrict__ Abf, const unsigned short* __restrict__ Bbf,
    const float* __restrict__ na, const float* __restrict__ nb,
    float* __restrict__ C)
{
  __shared__ __align__(16) char smem[49152];
  const int t = threadIdx.x;
  const int lane = t & 63;
  const int wid = t >> 6;
  const int wm = wid >> 1, wn = wid & 1;

  // XCD mapping (bijective, 8 XCDs x 512): 16x32-tile region per XCD.
  const int bid = blockIdx.x;
  const int x = bid & 7;
  const int k = bid >> 3;
  const int tr = ((x >> 1) << 4) + (k >> 5);   // tile row 0..63
  const int tc = ((x & 1) << 5) + (k & 31);    // tile col 0..63
  const int brow = tr << 7;
  const int bcol = tc << 7;

  // Staging: linear dest chunk + t*16; GLOBAL source col swizzled by the
  // involution f(b)=b^(((b>>7)&3)<<4) -> scolb = ((t&3)^((t>>3)&3))<<4.
  const int srow = t >> 2;                                   // 0..63
  const int scolb = (((t & 3) ^ ((t >> 3) & 3)) << 4);

  // Fragment ds_read offsets (within buf; add buf*16384 at use).
  int aoff[4], boff[4];
  #pragma unroll
  for (int f = 0; f < 4; ++f) {
    const int ra = wm * 64 + f * 16 + (lane & 15);
    aoff[f] = ra * 64 + (((lane >> 4) * 16) ^ (((ra >> 1) & 3) << 4));
    const int rb = wn * 64 + f * 16 + (lane & 15);
    boff[f] = 8192 + rb * 64 + (((lane >> 4) * 16) ^ (((rb >> 1) & 3) << 4));
  }

  const char* Ab = (const char*)Abf;
  const char* Bb = (const char*)Bbf;

  auto stage = [&](int buf, int kt) {
    #pragma unroll
    for (int h = 0; h < 2; ++h) {
      gload_lds16(Ab + (size_t)(brow + h * 64 + srow) * 512 + kt * 64 + scolb,
                  smem + buf * 16384 + h * 4096 + (wid << 10));
      gload_lds16(Bb + (size_t)(bcol + h * 64 + srow) * 512 + kt * 64 + scolb,
                  smem + buf * 16384 + 8192 + h * 4096 + (wid << 10));
    }
  };

  f32x4 acc[4][4] = {};

  // ---- prologue: 2 steps staged; wait only for step 0 ----
  stage(0, 0);
  stage(1, 1);
  asm volatile("s_waitcnt vmcnt(4)" ::: "memory");
  FULL_BARRIER();

  #pragma unroll
  for (int kt = 0; kt < NKT; ++kt) {
    const int cb = (kt % 3) * 16384;

    short8 af[4], bfv[4];
    #pragma unroll
    for (int f = 0; f < 4; ++f) {
      af[f]  = *(const short8*)(smem + cb + aoff[f]);
      bfv[f] = *(const short8*)(smem + cb + boff[f]);
    }
    if (kt + 2 < NKT) stage((kt + 2) % 3, kt + 2);

    __builtin_amdgcn_s_setprio(1);
    // Swapped operands: thread holds C[i][j0..j0+3].
    #pragma unroll
    for (int fm = 0; fm < 4; ++fm)
      #pragma unroll
      for (int fn = 0; fn < 4; ++fn)
        acc[fm][fn] = __builtin_amdgcn_mfma_f32_16x16x32_bf16(
            bfv[fn], af[fm], acc[fm][fn], 0, 0, 0);
    __builtin_amdgcn_s_setprio(0);

    if (kt < NKT - 1) {
      if (kt + 2 < NKT) { asm volatile("s_waitcnt vmcnt(4)" ::: "memory"); }
      else              { asm volatile("s_waitcnt vmcnt(0)" ::: "memory"); }
      FULL_BARRIER();
    }
  }

  // ---- lean epilogue: K = exp2(na + nb + 2*gamma*log2e*dot) ----
  // b4s hoisted (fm-invariant); f32x4 vector math -> v_pk_add/pk_fma;
  // raw v_exp_f32 (args in [-8,0], no fixups needed).
  const float c2 = 2.0f * GAMMA_F * LOG2E_F;
  f32x4 b4s[4];
  #pragma unroll
  for (int fn = 0; fn < 4; ++fn) {
    const int j0 = bcol + wn * 64 + fn * 16 + ((lane >> 4) << 2);
    b4s[fn] = *(const f32x4*)&nb[j0];
  }
  #pragma unroll
  for (int fm = 0; fm < 4; ++fm) {
    const int i = brow + wm * 64 + fm * 16 + (lane & 15);
    const float an = na[i];
    float* crow = C + (size_t)i * ND;
    #pragma unroll
    for (int fn = 0; fn < 4; ++fn) {
      const int j0 = bcol + wn * 64 + fn * 16 + ((lane >> 4) << 2);
      f32x4 arg = b4s[fn] + an;          // v_pk_add_f32 x2
      arg = acc[fm][fn] * c2 + arg;      // v_pk_fma_f32 x2
      f32x4 o;
      o[0] = fast_exp2(arg[0]);
      o[1] = fast_exp2(arg[1]);
      o[2] = fast_exp2(arg[2]);
      o[3] = fast_exp2(arg[3]);
      *(f32x4*)&crow[j0] = o;
    }
  }
}

// ---------------------------------------------------------------------------
// Fallback (tiny d_ws): 128x128 serial kernel, f32->bf16 inline.
// ---------------------------------------------------------------------------
__global__ __launch_bounds__(256) void rbf_gemm_fallback(
    const float* __restrict__ Af, const float* __restrict__ Bf,
    const float* __restrict__ na, const float* __restrict__ nb,
    float* __restrict__ C)
{
  __shared__ __align__(16) char smem[16384];
  const int t = threadIdx.x;
  const int lane = t & 63;
  const int wid = t >> 6;
  const int wm = wid >> 1, wn = wid & 1;
  const int bid = blockIdx.x;
  const int brow = (bid >> 6) << 7;
  const int bcol = (bid & 63) << 7;
  const int srow = t >> 2;
  const int scolb = (((t & 3) ^ ((t >> 3) & 3)) << 4);

  int aoff[4], boff[4];
  #pragma unroll
  for (int f = 0; f < 4; ++f) {
    const int ra = wm * 64 + f * 16 + (lane & 15);
    aoff[f] = ra * 64 + (((lane >> 4) * 16) ^ (((ra >> 1) & 3) << 4));
    const int rb = wn * 64 + f * 16 + (lane & 15);
    boff[f] = 8192 + rb * 64 + (((lane >> 4) * 16) ^ (((rb >> 1) & 3) << 4));
  }

  f32x4 acc[4][4] = {};
  for (int kt = 0; kt < 8; ++kt) {
    #pragma unroll
    for (int h = 0; h < 2; ++h) {
      const float* sa = Af + (size_t)(brow + h * 64 + srow) * KD + kt * 32 + (scolb >> 1);
      const float4 a0 = *(const float4*)sa;
      const float4 a1 = *(const float4*)(sa + 4);
      *(uint4*)(smem + h * 4096 + t * 16) = make_uint4(
          (unsigned)f2b(a0.x) | ((unsigned)f2b(a0.y) << 16),
          (unsigned)f2b(a0.z) | ((unsigned)f2b(a0.w) << 16),
          (unsigned)f2b(a1.x) | ((unsigned)f2b(a1.y) << 16),
          (unsigned)f2b(a1.z) | ((unsigned)f2b(a1.w) << 16));
      const float* sb = Bf + (size_t)(bcol + h * 64 + srow) * KD + kt * 32 + (scolb >> 1);
      const float4 b0 = *(const float4*)sb;
      const float4 b1 = *(const float4*)(sb + 4);
      *(uint4*)(smem + 8192 + h * 4096 + t * 16) = make_uint4(
          (unsigned)f2b(b0.x) | ((unsigned)f2b(b0.y) << 16),
          (unsigned)f2b(b0.z) | ((unsigned)f2b(b0.w) << 16),
          (unsigned)f2b(b1.x) | ((unsigned)f2b(b1.y) << 16),
          (unsigned)f2b(b1.z) | ((unsigned)f2b(b1.w) << 16));
    }
    __syncthreads();
    short8 af[4], bfv[4];
    #pragma unroll
    for (int f = 0; f < 4; ++f) {
      af[f]  = *(const short8*)(smem + aoff[f]);
      bfv[f] = *(const short8*)(smem + boff[f]);
    }
    #pragma unroll
    for (int fm = 0; fm < 4; ++fm)
      #pragma unroll
      for (int fn = 0; fn < 4; ++fn)
        acc[fm][fn] = __builtin_amdgcn_mfma_f32_16x16x32_bf16(
            bfv[fn], af[fm], acc[fm][fn], 0, 0, 0);
    __syncthreads();
  }

  const float c2 = 2.0f * GAMMA_F * LOG2E_F;
  #pragma unroll
  for (int fm = 0; fm < 4; ++fm) {
    const int i = brow + wm * 64 + fm * 16 + (lane & 15);
    const float an = na[i];
    float* crow = C + (size_t)i * ND;
    #pragma unroll
    for (int fn = 0; fn < 4; ++fn) {
      const int j0 = bcol + wn * 64 + fn * 16 + ((lane >> 4) << 2);
      const f32x4 b4 = *(const f32x4*)&nb[j0];
      f32x4 arg = b4 + an;
      arg = acc[fm][fn] * c2 + arg;
      f32x4 o;
      o[0] = fast_exp2(arg[0]);
      o[1] = fast_exp2(arg[1]);
      o[2] = fast_exp2(arg[2]);
      o[3] = fast_exp2(arg[3]);
      *(f32x4*)&crow[j0] = o;
    }
  }
}

// ---------------------------------------------------------------------------
extern "C" void kernel_launch(void* const* d_in, const int* in_sizes, int n_in,
                              void* d_out, int out_size, void* d_ws, size_t ws_size,
                              hipStream_t stream) {
  const float* A = (const float*)d_in[0];
  const float* B = (const float*)d_in[1];
  float* C = (float*)d_out;

  const size_t bfBytes = (size_t)ND * KD * 2;   // 4 MiB per matrix
  const size_t normBytes = (size_t)ND * 4;
  char* ws = (char*)d_ws;

  if (ws_size >= 2 * bfBytes + 2 * normBytes) {
    unsigned short* Abf = (unsigned short*)ws;
    unsigned short* Bbf = (unsigned short*)(ws + bfBytes);
    float* na = (float*)(ws + 2 * bfBytes);
    float* nb = (float*)(ws + 2 * bfBytes + normBytes);
    hipLaunchKernelGGL(norm_convert_kernel, dim3(2 * ND / 4), dim3(256), 0, stream,
                       A, B, Abf, Bbf, na, nb);
    hipLaunchKernelGGL(rbf_gemm_kernel, dim3((ND / 128) * (ND / 128)), dim3(256), 0,
                       stream, Abf, Bbf, na, nb, C);
  } else {
    float* na = (float*)ws;
    float* nb = (float*)(ws + normBytes);
    hipLaunchKernelGGL(norm_convert_kernel, dim3(2 * ND / 4), dim3(256), 0, stream,
                       A, B, (unsigned short*)nullptr, (unsigned short*)nullptr, na, nb);
    hipLaunchKernelGGL(rbf_gemm_fallback, dim3((ND / 128) * (ND / 128)), dim3(256), 0,
                       stream, A, B, na, nb, C);
  }
}